// Round 4
// baseline (1043.232 us; speedup 1.0000x reference)
//
#include <hip/hip_runtime.h>
#include <hip/hip_bf16.h>
#include <math.h>

// Problem constants (B=4, S=4096 -> T=16384 tokens)
#define TOKENS 16384
#define HD 1024
#define FD 2048
#define NEXP 8
#define RP_MAX (264 * 128)   // max padded routed rows (sum ceil(c_e/128)*128 <= 264*128)
#define MAX_MT 264           // max 128-row m-tiles (divisible by 8 for XCD swizzle)
#define NTN1 16              // gemm1 n-tiles: FD/128
#define NTN2 8               // gemm2 n-tiles: HD/128

typedef __bf16 bf16x8 __attribute__((ext_vector_type(8)));
typedef float f32x4 __attribute__((ext_vector_type(4)));
typedef unsigned short u16;
typedef unsigned int u32;

__device__ __forceinline__ u16 f2bf(float f) {
    union { float f; u32 u; } v; v.f = f;
    return (u16)((v.u + 0x7FFFu + ((v.u >> 16) & 1u)) >> 16);
}

#define GLOAD16(g, l) __builtin_amdgcn_global_load_lds( \
    (const __attribute__((address_space(1))) u32*)(g),  \
    (__attribute__((address_space(3))) u32*)(l), 16, 0, 0)

// ---------------- routing ----------------

__global__ void init_routing(int* sorted_rid, int* counts, int* fill, int* numTiles) {
    int i = blockIdx.x * blockDim.x + threadIdx.x;
    if (i < RP_MAX) sorted_rid[i] = -1;
    if (i < NEXP) { counts[i] = 0; fill[i] = 0; }
    if (i == 0) *numTiles = 0;
}

__global__ void zero_f32(float4* p, int n4) {
    int i = blockIdx.x * blockDim.x + threadIdx.x;
    if (i < n4) p[i] = make_float4(0.f, 0.f, 0.f, 0.f);
}

__global__ void count_kernel(const int* __restrict__ te, int* counts) {
    int j = blockIdx.x * blockDim.x + threadIdx.x;
    if (j < TOKENS * 2) atomicAdd(&counts[te[j]], 1);
}

__global__ void scan_kernel(const int* __restrict__ counts, int* offs,
                            int* tileE, int* tileRow, int* numTiles) {
    if (blockIdx.x == 0 && threadIdx.x == 0) {
        int o = 0, t = 0;
        for (int e = 0; e < NEXP; e++) {
            offs[e] = o;
            int nt = (counts[e] + 127) >> 7;
            for (int i = 0; i < nt; i++) { tileE[t] = e; tileRow[t] = o + i * 128; t++; }
            o += nt * 128;
        }
        *numTiles = t;
    }
}

__global__ void scatter_kernel(const int* __restrict__ te, const int* __restrict__ offs,
                               int* fill, int* sorted_rid) {
    int j = blockIdx.x * blockDim.x + threadIdx.x;
    if (j < TOKENS * 2) {
        int e = te[j];
        int p = offs[e] + atomicAdd(&fill[e], 1);
        sorted_rid[p] = j;
    }
}

// ---------------- conversions ----------------

__global__ void convert_x(const float* __restrict__ x, u16* __restrict__ xb) {
    int i = blockIdx.x * blockDim.x + threadIdx.x;   // one thread = 8 elems
    const float4* xv = (const float4*)x;
    float4 a = xv[i * 2], b = xv[i * 2 + 1];
    union { u16 s[8]; uint4 v; } o;
    o.s[0] = f2bf(a.x); o.s[1] = f2bf(a.y); o.s[2] = f2bf(a.z); o.s[3] = f2bf(a.w);
    o.s[4] = f2bf(b.x); o.s[5] = f2bf(b.y); o.s[6] = f2bf(b.z); o.s[7] = f2bf(b.w);
    *(uint4*)(xb + (size_t)i * 8) = o.v;
}

// in: [E][K][N] f32  ->  out: [E][N][K] bf16
__global__ void transpose_conv(const float* __restrict__ in, u16* __restrict__ out,
                               int K, int N) {
    __shared__ float tile[32][33];
    int e = blockIdx.z;
    int n0 = blockIdx.x * 32, k0 = blockIdx.y * 32;
    const float* src = in + (size_t)e * K * N;
    u16* dst = out + (size_t)e * N * K;
    int tx = threadIdx.x, ty = threadIdx.y;
    #pragma unroll
    for (int j = 0; j < 32; j += 8)
        tile[ty + j][tx] = src[(size_t)(k0 + ty + j) * N + n0 + tx];
    __syncthreads();
    #pragma unroll
    for (int j = 0; j < 32; j += 8)
        dst[(size_t)(n0 + ty + j) * K + k0 + tx] = f2bf(tile[tx][ty + j]);
}

// ==================================================================
// 128x128 grouped-GEMM core, BK=64, 4 waves, 2-phase double-buffered
// K-loop (T3-min): stage tile t+1 BEFORE computing tile t; one
// vmcnt(0)+barrier per K-tile, placed AFTER the MFMA cluster so the
// 8 staging loads overlap ds_read + 32 MFMAs.
// LDS XOR swizzle (T2, verified 0 conflicts): physical 16B slot kc of
// row r holds logical slot kc^(r&7); staged via pre-swizzled GLOBAL
// source (linear LDS dest, rule #21).
// XCD swizzle (T1): mt pinned to one XCD, n-tiles consecutive.
// ==================================================================

// ---------------- grouped GEMM 1: H_act = gelu(X[gather] @ w1 + b1) ----------------

__global__ __launch_bounds__(256, 2) void gemm1_kernel(
    const u16* __restrict__ Xb, const u16* __restrict__ W1t,
    const float* __restrict__ b1, const int* __restrict__ sorted_rid,
    const int* __restrict__ tileE, const int* __restrict__ tileRow,
    const int* __restrict__ numTiles, u16* __restrict__ Hact)
{
    // XCD-bijective decode: bid = ((mt>>3)*NTN1 + nt)*8 + (mt&7)
    int bid = blockIdx.x;
    int xcd = bid & 7, slot = bid >> 3;
    int mt = xcd + (slot / NTN1) * 8;
    int n0 = (slot % NTN1) * 128;
    if (mt >= *numTiles) return;
    int e = tileE[mt];
    int row0 = tileRow[mt];

    __shared__ __align__(16) u16 As[2][128 * 64];
    __shared__ __align__(16) u16 Bs[2][128 * 64];
    char* AsB = (char*)&As[0][0];
    char* BsB = (char*)&Bs[0][0];

    int tid = threadIdx.x;
    int wave = tid >> 6, lane = tid & 63;
    int laneR = lane & 15;

    const u16* gA[4]; const u16* gB[4];
    #pragma unroll
    for (int i = 0; i < 4; i++) {
        int c = i * 256 + tid;
        int r = c >> 3, kc = c & 7;
        int kcs = kc ^ (r & 7);                  // pre-swizzled source slot
        int rid = sorted_rid[row0 + r];
        int tok = rid < 0 ? 0 : (rid >> 1);
        gA[i] = Xb + (size_t)tok * HD + kcs * 8;
        gB[i] = W1t + ((size_t)e * FD + (n0 + r)) * HD + kcs * 8;
    }
    // stage one BK=64 tile into buffer `buf`, advance source pointers
    auto stage = [&](int buf) {
        #pragma unroll
        for (int i = 0; i < 4; i++)
            GLOAD16(gA[i], AsB + buf * 16384 + i * 4096 + wave * 1024);
        #pragma unroll
        for (int i = 0; i < 4; i++)
            GLOAD16(gB[i], BsB + buf * 16384 + i * 4096 + wave * 1024);
        #pragma unroll
        for (int i = 0; i < 4; i++) { gA[i] += 64; gB[i] += 64; }
    };

    f32x4 acc[4][4] = {};

    int wr = wave >> 1, wc = wave & 1;
    int off0 = (((lane >> 4) ^ (lane & 7)) << 4);
    int off1 = off0 ^ 64;
    const char* Abase = AsB + (wr * 64 + laneR) * 128;
    const char* Bbase = BsB + (wc * 64 + laneR) * 128;

    const int NT = HD / 64;
    stage(0);
    asm volatile("s_waitcnt vmcnt(0)" ::: "memory");
    __builtin_amdgcn_s_barrier();

    int cur = 0;
    for (int t = 0; t < NT; t++) {
        if (t + 1 < NT) stage(cur ^ 1);          // loads fly under compute
        __builtin_amdgcn_sched_barrier(0);
        bf16x8 a[2][4], b[2][4];
        #pragma unroll
        for (int kk = 0; kk < 2; kk++) {
            int off = cur * 16384 + (kk ? off1 : off0);
            #pragma unroll
            for (int m = 0; m < 4; m++) a[kk][m] = *(const bf16x8*)(Abase + m * 2048 + off);
            #pragma unroll
            for (int n = 0; n < 4; n++) b[kk][n] = *(const bf16x8*)(Bbase + n * 2048 + off);
        }
        asm volatile("s_waitcnt lgkmcnt(0)" ::: "memory");
        __builtin_amdgcn_sched_barrier(0);
        __builtin_amdgcn_s_setprio(1);
        #pragma unroll
        for (int kk = 0; kk < 2; kk++)
            #pragma unroll
            for (int m = 0; m < 4; m++)
                #pragma unroll
                for (int n = 0; n < 4; n++)
                    acc[m][n] = __builtin_amdgcn_mfma_f32_16x16x32_bf16(a[kk][m], b[kk][n], acc[m][n], 0, 0, 0);
        __builtin_amdgcn_s_setprio(0);
        asm volatile("s_waitcnt vmcnt(0)" ::: "memory");
        __builtin_amdgcn_s_barrier();
        cur ^= 1;
    }

    // epilogue: bias + exact gelu -> bf16 store
    const float* b1e = b1 + e * FD + n0;
    #pragma unroll
    for (int n = 0; n < 4; n++) {
        int col = wc * 64 + n * 16 + laneR;
        float bias = b1e[col];
        #pragma unroll
        for (int m = 0; m < 4; m++) {
            int rbase = wr * 64 + m * 16 + (lane >> 4) * 4;
            #pragma unroll
            for (int r = 0; r < 4; r++) {
                float v = acc[m][n][r] + bias;
                v = 0.5f * v * (1.0f + erff(v * 0.70710678118f));
                Hact[(size_t)(row0 + rbase + r) * FD + n0 + col] = f2bf(v);
            }
        }
    }
}

// ---------------- grouped GEMM 2: y += fw * (H_act @ w2 + b2) ----------------

__global__ __launch_bounds__(256, 2) void gemm2_kernel(
    const u16* __restrict__ Hact, const u16* __restrict__ W2t,
    const float* __restrict__ b2, const float* __restrict__ ew,
    const int* __restrict__ sorted_rid,
    const int* __restrict__ tileE, const int* __restrict__ tileRow,
    const int* __restrict__ numTiles, float* __restrict__ y)
{
    int bid = blockIdx.x;
    int xcd = bid & 7, slot = bid >> 3;
    int mt = xcd + (slot / NTN2) * 8;
    int n0 = (slot % NTN2) * 128;
    if (mt >= *numTiles) return;
    int e = tileE[mt];
    int row0 = tileRow[mt];

    __shared__ __align__(16) u16 As[2][128 * 64];
    __shared__ __align__(16) u16 Bs[2][128 * 64];
    char* AsB = (char*)&As[0][0];
    char* BsB = (char*)&Bs[0][0];

    int tid = threadIdx.x;
    int wave = tid >> 6, lane = tid & 63;
    int laneR = lane & 15;

    const u16* gA[4]; const u16* gB[4];
    #pragma unroll
    for (int i = 0; i < 4; i++) {
        int c = i * 256 + tid;
        int r = c >> 3, kc = c & 7;
        int kcs = kc ^ (r & 7);
        gA[i] = Hact + (size_t)(row0 + r) * FD + kcs * 8;
        gB[i] = W2t + ((size_t)e * HD + (n0 + r)) * FD + kcs * 8;
    }
    auto stage = [&](int buf) {
        #pragma unroll
        for (int i = 0; i < 4; i++)
            GLOAD16(gA[i], AsB + buf * 16384 + i * 4096 + wave * 1024);
        #pragma unroll
        for (int i = 0; i < 4; i++)
            GLOAD16(gB[i], BsB + buf * 16384 + i * 4096 + wave * 1024);
        #pragma unroll
        for (int i = 0; i < 4; i++) { gA[i] += 64; gB[i] += 64; }
    };

    f32x4 acc[4][4] = {};

    int wr = wave >> 1, wc = wave & 1;
    int off0 = (((lane >> 4) ^ (lane & 7)) << 4);
    int off1 = off0 ^ 64;
    const char* Abase = AsB + (wr * 64 + laneR) * 128;
    const char* Bbase = BsB + (wc * 64 + laneR) * 128;

    const int NT = FD / 64;
    stage(0);
    asm volatile("s_waitcnt vmcnt(0)" ::: "memory");
    __builtin_amdgcn_s_barrier();

    int cur = 0;
    for (int t = 0; t < NT; t++) {
        if (t + 1 < NT) stage(cur ^ 1);
        __builtin_amdgcn_sched_barrier(0);
        bf16x8 a[2][4], b[2][4];
        #pragma unroll
        for (int kk = 0; kk < 2; kk++) {
            int off = cur * 16384 + (kk ? off1 : off0);
            #pragma unroll
            for (int m = 0; m < 4; m++) a[kk][m] = *(const bf16x8*)(Abase + m * 2048 + off);
            #pragma unroll
            for (int n = 0; n < 4; n++) b[kk][n] = *(const bf16x8*)(Bbase + n * 2048 + off);
        }
        asm volatile("s_waitcnt lgkmcnt(0)" ::: "memory");
        __builtin_amdgcn_sched_barrier(0);
        __builtin_amdgcn_s_setprio(1);
        #pragma unroll
        for (int kk = 0; kk < 2; kk++)
            #pragma unroll
            for (int m = 0; m < 4; m++)
                #pragma unroll
                for (int n = 0; n < 4; n++)
                    acc[m][n] = __builtin_amdgcn_mfma_f32_16x16x32_bf16(a[kk][m], b[kk][n], acc[m][n], 0, 0, 0);
        __builtin_amdgcn_s_setprio(0);
        asm volatile("s_waitcnt vmcnt(0)" ::: "memory");
        __builtin_amdgcn_s_barrier();
        cur ^= 1;
    }

    // epilogue: bias, routing weight, atomic scatter-add into y[token]
    const float* b2e = b2 + e * HD + n0;
    #pragma unroll
    for (int m = 0; m < 4; m++) {
        int rbase = wr * 64 + m * 16 + (lane >> 4) * 4;
        #pragma unroll
        for (int r = 0; r < 4; r++) {
            int rid = sorted_rid[row0 + rbase + r];
            if (rid < 0) continue;               // padding row
            float fw = ew[rid];
            float* yrow = y + (size_t)(rid >> 1) * HD + n0;
            #pragma unroll
            for (int n = 0; n < 4; n++) {
                int col = wc * 64 + n * 16 + laneR;
                atomicAdd(&yrow[col], (acc[m][n][r] + b2e[col]) * fw);
            }
        }
    }
}

// ---------------- launch ----------------

extern "C" void kernel_launch(void* const* d_in, const int* in_sizes, int n_in,
                              void* d_out, int out_size, void* d_ws, size_t ws_size,
                              hipStream_t stream) {
    const float* x  = (const float*)d_in[0];
    const float* ew = (const float*)d_in[1];
    const int*   te = (const int*)d_in[2];
    const float* w1 = (const float*)d_in[3];
    const float* b1 = (const float*)d_in[4];
    const float* w2 = (const float*)d_in[5];
    const float* b2 = (const float*)d_in[6];
    float* y = (float*)d_out;

    char* ws = (char*)d_ws;
    u16* Xb   = (u16*)(ws);                      // 33,554,432 B
    u16* W1t  = (u16*)(ws + 33554432);           // 33,554,432 B
    u16* W2t  = (u16*)(ws + 67108864);           // 33,554,432 B
    u16* Hact = (u16*)(ws + 100663296);          // 138,412,032 B
    char* ip  = ws + 239075328;
    int* counts   = (int*)(ip);
    int* fill     = (int*)(ip + 32);
    int* offs     = (int*)(ip + 64);
    int* numTiles = (int*)(ip + 96);
    int* tileE    = (int*)(ip + 128);
    int* tileRow  = (int*)(ip + 128 + 1056);
    int* sorted   = (int*)(ip + 4096);           // RP_MAX ints

    // routing
    init_routing<<<(RP_MAX + 255) / 256, 256, 0, stream>>>(sorted, counts, fill, numTiles);
    zero_f32<<<(out_size / 4 + 255) / 256, 256, 0, stream>>>((float4*)y, out_size / 4);
    count_kernel<<<(TOKENS * 2 + 255) / 256, 256, 0, stream>>>(te, counts);
    scan_kernel<<<1, 64, 0, stream>>>(counts, offs, tileE, tileRow, numTiles);
    scatter_kernel<<<(TOKENS * 2 + 255) / 256, 256, 0, stream>>>(te, offs, fill, sorted);

    // conversions
    convert_x<<<(TOKENS * HD / 8 + 255) / 256, 256, 0, stream>>>(x, Xb);
    transpose_conv<<<dim3(FD / 32, HD / 32, NEXP), dim3(32, 8), 0, stream>>>(w1, W1t, HD, FD);
    transpose_conv<<<dim3(HD / 32, FD / 32, NEXP), dim3(32, 8), 0, stream>>>(w2, W2t, FD, HD);

    // grouped GEMMs (flat grid, XCD-swizzled block decode)
    gemm1_kernel<<<MAX_MT * NTN1, 256, 0, stream>>>(
        Xb, W1t, b1, sorted, tileE, tileRow, numTiles, Hact);
    gemm2_kernel<<<MAX_MT * NTN2, 256, 0, stream>>>(
        Hact, W2t, b2, ew, sorted, tileE, tileRow, numTiles, y);
}

// Round 5
// 699.948 us; speedup vs baseline: 1.4904x; 1.4904x over previous
//
#include <hip/hip_runtime.h>
#include <hip/hip_bf16.h>
#include <math.h>

// Problem constants (B=4, S=4096 -> T=16384 tokens)
#define TOKENS 16384
#define HD 1024
#define FD 2048
#define NEXP 8
#define RP_MAX (264 * 128)   // max padded routed rows (sum ceil(c_e/128)*128 <= 264*128)
#define MAX_MT 264           // max 128-row m-tiles (divisible by 8 for XCD swizzle)
#define NTN1 16              // gemm1 n-tiles: FD/128
#define NTN2 8               // gemm2 n-tiles: HD/128

typedef __bf16 bf16x8 __attribute__((ext_vector_type(8)));
typedef float f32x4 __attribute__((ext_vector_type(4)));
typedef unsigned short u16;
typedef unsigned int u32;

__device__ __forceinline__ u16 f2bf(float f) {
    union { float f; u32 u; } v; v.f = f;
    return (u16)((v.u + 0x7FFFu + ((v.u >> 16) & 1u)) >> 16);
}

#define GLOAD16(g, l) __builtin_amdgcn_global_load_lds( \
    (const __attribute__((address_space(1))) u32*)(g),  \
    (__attribute__((address_space(3))) u32*)(l), 16, 0, 0)

// ---------------- routing ----------------

__global__ void init_routing(int* sorted_rid, int* counts, int* fill, int* numTiles) {
    int i = blockIdx.x * blockDim.x + threadIdx.x;
    if (i < RP_MAX) sorted_rid[i] = -1;
    if (i < NEXP) { counts[i] = 0; fill[i] = 0; }
    if (i == 0) *numTiles = 0;
}

__global__ void count_kernel(const int* __restrict__ te, int* counts) {
    int j = blockIdx.x * blockDim.x + threadIdx.x;
    if (j < TOKENS * 2) atomicAdd(&counts[te[j]], 1);
}

__global__ void scan_kernel(const int* __restrict__ counts, int* offs,
                            int* tileE, int* tileRow, int* numTiles) {
    if (blockIdx.x == 0 && threadIdx.x == 0) {
        int o = 0, t = 0;
        for (int e = 0; e < NEXP; e++) {
            offs[e] = o;
            int nt = (counts[e] + 127) >> 7;
            for (int i = 0; i < nt; i++) { tileE[t] = e; tileRow[t] = o + i * 128; t++; }
            o += nt * 128;
        }
        *numTiles = t;
    }
}

// scatter + inverse map (rid -> padded slot) for the non-atomic combine
__global__ void scatter_kernel(const int* __restrict__ te, const int* __restrict__ offs,
                               int* fill, int* sorted_rid, int* inv) {
    int j = blockIdx.x * blockDim.x + threadIdx.x;
    if (j < TOKENS * 2) {
        int e = te[j];
        int p = offs[e] + atomicAdd(&fill[e], 1);
        sorted_rid[p] = j;
        inv[j] = p;
    }
}

// ---------------- conversions ----------------

__global__ void convert_x(const float* __restrict__ x, u16* __restrict__ xb) {
    int i = blockIdx.x * blockDim.x + threadIdx.x;   // one thread = 8 elems
    const float4* xv = (const float4*)x;
    float4 a = xv[i * 2], b = xv[i * 2 + 1];
    union { u16 s[8]; uint4 v; } o;
    o.s[0] = f2bf(a.x); o.s[1] = f2bf(a.y); o.s[2] = f2bf(a.z); o.s[3] = f2bf(a.w);
    o.s[4] = f2bf(b.x); o.s[5] = f2bf(b.y); o.s[6] = f2bf(b.z); o.s[7] = f2bf(b.w);
    *(uint4*)(xb + (size_t)i * 8) = o.v;
}

// in: [E][K][N] f32  ->  out: [E][N][K] bf16
__global__ void transpose_conv(const float* __restrict__ in, u16* __restrict__ out,
                               int K, int N) {
    __shared__ float tile[32][33];
    int e = blockIdx.z;
    int n0 = blockIdx.x * 32, k0 = blockIdx.y * 32;
    const float* src = in + (size_t)e * K * N;
    u16* dst = out + (size_t)e * N * K;
    int tx = threadIdx.x, ty = threadIdx.y;
    #pragma unroll
    for (int j = 0; j < 32; j += 8)
        tile[ty + j][tx] = src[(size_t)(k0 + ty + j) * N + n0 + tx];
    __syncthreads();
    #pragma unroll
    for (int j = 0; j < 32; j += 8)
        dst[(size_t)(n0 + ty + j) * K + k0 + tx] = f2bf(tile[tx][ty + j]);
}

// ==================================================================
// 128x128 grouped-GEMM core (round-2 proven): BK=64, 4 waves, single
// LDS buffer, stage -> sync -> 32 MFMA -> sync. T2 XOR swizzle via
// pre-swizzled global source (0 bank conflicts). T1 XCD-bijective
// flat grid: mt pinned to one XCD, n-tiles consecutive (FETCH 612->221MB).
// ==================================================================

// ---------------- grouped GEMM 1: H_act = gelu(X[gather] @ w1 + b1) ----------------

__global__ __launch_bounds__(256, 2) void gemm1_kernel(
    const u16* __restrict__ Xb, const u16* __restrict__ W1t,
    const float* __restrict__ b1, const int* __restrict__ sorted_rid,
    const int* __restrict__ tileE, const int* __restrict__ tileRow,
    const int* __restrict__ numTiles, u16* __restrict__ Hact)
{
    // XCD-bijective decode: bid = ((mt>>3)*NTN1 + nt)*8 + (mt&7)
    int bid = blockIdx.x;
    int xcd = bid & 7, slot = bid >> 3;
    int mt = xcd + (slot / NTN1) * 8;
    int n0 = (slot % NTN1) * 128;
    if (mt >= *numTiles) return;
    int e = tileE[mt];
    int row0 = tileRow[mt];

    __shared__ __align__(16) u16 As[128 * 64];
    __shared__ __align__(16) u16 Bs[128 * 64];

    int tid = threadIdx.x;
    int wave = tid >> 6, lane = tid & 63;
    int laneR = lane & 15;

    const u16* gA[4]; const u16* gB[4];
    #pragma unroll
    for (int i = 0; i < 4; i++) {
        int c = i * 256 + tid;
        int r = c >> 3, kc = c & 7;
        int kcs = kc ^ (r & 7);                  // pre-swizzled source slot
        int rid = sorted_rid[row0 + r];
        int tok = rid < 0 ? 0 : (rid >> 1);
        gA[i] = Xb + (size_t)tok * HD + kcs * 8;
        gB[i] = W1t + ((size_t)e * FD + (n0 + r)) * HD + kcs * 8;
    }
    char* AsB = (char*)As; char* BsB = (char*)Bs;

    f32x4 acc[4][4] = {};

    int wr = wave >> 1, wc = wave & 1;
    int off0 = (((lane >> 4) ^ (lane & 7)) << 4);
    int off1 = off0 ^ 64;
    const char* Abase = AsB + (wr * 64 + laneR) * 128;
    const char* Bbase = BsB + (wc * 64 + laneR) * 128;

    for (int kt = 0; kt < HD / 64; kt++) {
        #pragma unroll
        for (int i = 0; i < 4; i++)
            GLOAD16(gA[i], AsB + i * 4096 + wave * 1024);
        #pragma unroll
        for (int i = 0; i < 4; i++)
            GLOAD16(gB[i], BsB + i * 4096 + wave * 1024);
        #pragma unroll
        for (int i = 0; i < 4; i++) { gA[i] += 64; gB[i] += 64; }
        __syncthreads();   // drains vmcnt(0) -> staged tile visible
        #pragma unroll
        for (int kk = 0; kk < 2; kk++) {
            int off = kk ? off1 : off0;
            bf16x8 a[4], b[4];
            #pragma unroll
            for (int m = 0; m < 4; m++) a[m] = *(const bf16x8*)(Abase + m * 2048 + off);
            #pragma unroll
            for (int n = 0; n < 4; n++) b[n] = *(const bf16x8*)(Bbase + n * 2048 + off);
            #pragma unroll
            for (int m = 0; m < 4; m++)
                #pragma unroll
                for (int n = 0; n < 4; n++)
                    acc[m][n] = __builtin_amdgcn_mfma_f32_16x16x32_bf16(a[m], b[n], acc[m][n], 0, 0, 0);
        }
        __syncthreads();
    }

    // epilogue: bias + exact gelu -> bf16 store
    const float* b1e = b1 + e * FD + n0;
    #pragma unroll
    for (int n = 0; n < 4; n++) {
        int col = wc * 64 + n * 16 + laneR;
        float bias = b1e[col];
        #pragma unroll
        for (int m = 0; m < 4; m++) {
            int rbase = wr * 64 + m * 16 + (lane >> 4) * 4;
            #pragma unroll
            for (int r = 0; r < 4; r++) {
                float v = acc[m][n][r] + bias;
                v = 0.5f * v * (1.0f + erff(v * 0.70710678118f));
                Hact[(size_t)(row0 + rbase + r) * FD + n0 + col] = f2bf(v);
            }
        }
    }
}

// ---------------- grouped GEMM 2: Out2[slot] = H_act @ w2 + b2 (bf16) ----------------

__global__ __launch_bounds__(256, 2) void gemm2_kernel(
    const u16* __restrict__ Hact, const u16* __restrict__ W2t,
    const float* __restrict__ b2,
    const int* __restrict__ tileE, const int* __restrict__ tileRow,
    const int* __restrict__ numTiles, u16* __restrict__ Out2)
{
    int bid = blockIdx.x;
    int xcd = bid & 7, slot = bid >> 3;
    int mt = xcd + (slot / NTN2) * 8;
    int n0 = (slot % NTN2) * 128;
    if (mt >= *numTiles) return;
    int e = tileE[mt];
    int row0 = tileRow[mt];

    __shared__ __align__(16) u16 As[128 * 64];
    __shared__ __align__(16) u16 Bs[128 * 64];

    int tid = threadIdx.x;
    int wave = tid >> 6, lane = tid & 63;
    int laneR = lane & 15;

    const u16* gA[4]; const u16* gB[4];
    #pragma unroll
    for (int i = 0; i < 4; i++) {
        int c = i * 256 + tid;
        int r = c >> 3, kc = c & 7;
        int kcs = kc ^ (r & 7);
        gA[i] = Hact + (size_t)(row0 + r) * FD + kcs * 8;
        gB[i] = W2t + ((size_t)e * HD + (n0 + r)) * FD + kcs * 8;
    }
    char* AsB = (char*)As; char* BsB = (char*)Bs;

    f32x4 acc[4][4] = {};

    int wr = wave >> 1, wc = wave & 1;
    int off0 = (((lane >> 4) ^ (lane & 7)) << 4);
    int off1 = off0 ^ 64;
    const char* Abase = AsB + (wr * 64 + laneR) * 128;
    const char* Bbase = BsB + (wc * 64 + laneR) * 128;

    for (int kt = 0; kt < FD / 64; kt++) {
        #pragma unroll
        for (int i = 0; i < 4; i++)
            GLOAD16(gA[i], AsB + i * 4096 + wave * 1024);
        #pragma unroll
        for (int i = 0; i < 4; i++)
            GLOAD16(gB[i], BsB + i * 4096 + wave * 1024);
        #pragma unroll
        for (int i = 0; i < 4; i++) { gA[i] += 64; gB[i] += 64; }
        __syncthreads();
        #pragma unroll
        for (int kk = 0; kk < 2; kk++) {
            int off = kk ? off1 : off0;
            bf16x8 a[4], b[4];
            #pragma unroll
            for (int m = 0; m < 4; m++) a[m] = *(const bf16x8*)(Abase + m * 2048 + off);
            #pragma unroll
            for (int n = 0; n < 4; n++) b[n] = *(const bf16x8*)(Bbase + n * 2048 + off);
            #pragma unroll
            for (int m = 0; m < 4; m++)
                #pragma unroll
                for (int n = 0; n < 4; n++)
                    acc[m][n] = __builtin_amdgcn_mfma_f32_16x16x32_bf16(a[m], b[n], acc[m][n], 0, 0, 0);
        }
        __syncthreads();
    }

    // epilogue: bias -> plain bf16 store into slot-major Out2 (no atomics)
    const float* b2e = b2 + e * HD + n0;
    #pragma unroll
    for (int m = 0; m < 4; m++) {
        int rbase = wr * 64 + m * 16 + (lane >> 4) * 4;
        #pragma unroll
        for (int r = 0; r < 4; r++) {
            u16* orow = Out2 + (size_t)(row0 + rbase + r) * HD + n0;
            #pragma unroll
            for (int n = 0; n < 4; n++) {
                int col = wc * 64 + n * 16 + laneR;
                orow[col] = f2bf(acc[m][n][r] + b2e[col]);
            }
        }
    }
}

// ---------------- combine: y[t] = w0*Out2[inv[2t]] + w1*Out2[inv[2t+1]] ----------------

__global__ void combine_kernel(const u16* __restrict__ Out2, const int* __restrict__ inv,
                               const float* __restrict__ ew, float* __restrict__ y) {
    int i = blockIdx.x * blockDim.x + threadIdx.x;   // one thread = 8 cols of one token
    int tok = i >> 7;                                // 128 chunks of 8 per token
    int c0 = (i & 127) << 3;
    int s0 = inv[2 * tok], s1 = inv[2 * tok + 1];
    float w0 = ew[2 * tok], w1 = ew[2 * tok + 1];
    union { uint4 v; u16 s[8]; } a, b;
    a.v = *(const uint4*)(Out2 + (size_t)s0 * HD + c0);
    b.v = *(const uint4*)(Out2 + (size_t)s1 * HD + c0);
    float out[8];
    #pragma unroll
    for (int j = 0; j < 8; j++) {
        union { u32 u; float f; } fa, fb;
        fa.u = (u32)a.s[j] << 16;
        fb.u = (u32)b.s[j] << 16;
        out[j] = w0 * fa.f + w1 * fb.f;
    }
    float4* yp = (float4*)(y + (size_t)tok * HD + c0);
    yp[0] = *(const float4*)&out[0];
    yp[1] = *(const float4*)&out[4];
}

// ---------------- launch ----------------

extern "C" void kernel_launch(void* const* d_in, const int* in_sizes, int n_in,
                              void* d_out, int out_size, void* d_ws, size_t ws_size,
                              hipStream_t stream) {
    const float* x  = (const float*)d_in[0];
    const float* ew = (const float*)d_in[1];
    const int*   te = (const int*)d_in[2];
    const float* w1 = (const float*)d_in[3];
    const float* b1 = (const float*)d_in[4];
    const float* w2 = (const float*)d_in[5];
    const float* b2 = (const float*)d_in[6];
    float* y = (float*)d_out;

    char* ws = (char*)d_ws;
    // overlays: W2t over Xb (w2 transposed AFTER gemm1); Out2 over W1t.
    u16* Xb   = (u16*)(ws);                      // [0, 33554432)
    u16* W2t  = (u16*)(ws);                      //   overlays Xb
    u16* W1t  = (u16*)(ws + 33554432);           // [33554432, 67108864)
    u16* Out2 = (u16*)(ws + 33554432);           //   overlays W1t, 69,206,016 B
    u16* Hact = (u16*)(ws + 102760448);          // 138,412,032 B (33792 x 2048 bf16)
    char* ip  = ws + 241172480;
    int* counts   = (int*)(ip);
    int* fill     = (int*)(ip + 32);
    int* offs     = (int*)(ip + 64);
    int* numTiles = (int*)(ip + 96);
    int* tileE    = (int*)(ip + 128);            // 1056 B
    int* tileRow  = (int*)(ip + 1184);           // 1056 B
    int* sorted   = (int*)(ip + 4096);           // 135,168 B
    int* inv      = (int*)(ip + 139264);         // 131,072 B

    // routing
    init_routing<<<(RP_MAX + 255) / 256, 256, 0, stream>>>(sorted, counts, fill, numTiles);
    count_kernel<<<(TOKENS * 2 + 255) / 256, 256, 0, stream>>>(te, counts);
    scan_kernel<<<1, 64, 0, stream>>>(counts, offs, tileE, tileRow, numTiles);
    scatter_kernel<<<(TOKENS * 2 + 255) / 256, 256, 0, stream>>>(te, offs, fill, sorted, inv);

    // conversions needed by gemm1
    convert_x<<<(TOKENS * HD / 8 + 255) / 256, 256, 0, stream>>>(x, Xb);
    transpose_conv<<<dim3(FD / 32, HD / 32, NEXP), dim3(32, 8), 0, stream>>>(w1, W1t, HD, FD);

    // grouped GEMM 1
    gemm1_kernel<<<MAX_MT * NTN1, 256, 0, stream>>>(
        Xb, W1t, b1, sorted, tileE, tileRow, numTiles, Hact);

    // w2 transpose AFTER gemm1 (W2t overlays Xb)
    transpose_conv<<<dim3(HD / 32, FD / 32, NEXP), dim3(32, 8), 0, stream>>>(w2, W2t, FD, HD);

    // grouped GEMM 2 (plain stores, no atomics)
    gemm2_kernel<<<MAX_MT * NTN2, 256, 0, stream>>>(
        Hact, W2t, b2, tileE, tileRow, numTiles, Out2);

    // weighted topk combine
    combine_kernel<<<(TOKENS * 128) / 256, 256, 0, stream>>>(Out2, inv, ew, y);
}